// Round 3
// baseline (132.411 us; speedup 1.0000x reference)
//
#include <hip/hip_runtime.h>
#include <hip/hip_bf16.h>
#include <math.h>

// Problem constants
#define N_TOK 16384
#define I_DIM 128
#define O_DIM 128
#define G_DIM 16
// GEMM tiling
#define BN 32                    // n-rows per block (grid = 512 -> 2 blocks/CU)
#define KC 128                   // k per chunk (4 i-values x 16 g x {cos,sin})
#define NCHUNK 32                // chunk c covers i = c*4 .. c*4+3
#define A_STRIDE 136             // bf16 elems per LDS A row (272 B, padded)
#define C_STRIDE 132             // floats per LDS C row (epilogue)

typedef __bf16 bf16x8 __attribute__((ext_vector_type(8)));
typedef float  f32x4  __attribute__((ext_vector_type(4)));

// ---------------------------------------------------------------------------
// Pack cos/sin amplitudes (O,I,G) fp32 -> bf16 Bpack[c][o][kk]
//   kk = il*32 + g*2 + s  (s: 0=cos 1=sin),  i = c*4 + il
// Coalesced float4 reads; 16 B writes.
// Thread u -> (o = u>>9, i = (u>>2)&127, gq = u&3) handles g = 4*gq..4*gq+3.
// ---------------------------------------------------------------------------
__global__ __launch_bounds__(256) void fkan_pack_b(
    const float* __restrict__ cosA, const float* __restrict__ sinA,
    __hip_bfloat16* __restrict__ Bp)
{
    int u  = blockIdx.x * 256 + threadIdx.x;       // 0 .. 65535
    int gq = u & 3;
    int i  = (u >> 2) & 127;
    int o  = u >> 9;
    int base = (o * I_DIM + i) * G_DIM + gq * 4;
    float4 cv = *(const float4*)(cosA + base);
    float4 sv = *(const float4*)(sinA + base);
    union { __bf16 h[8]; uint4 v; } w;
    w.h[0] = (__bf16)cv.x; w.h[1] = (__bf16)sv.x;
    w.h[2] = (__bf16)cv.y; w.h[3] = (__bf16)sv.y;
    w.h[4] = (__bf16)cv.z; w.h[5] = (__bf16)sv.z;
    w.h[6] = (__bf16)cv.w; w.h[7] = (__bf16)sv.w;
    int c   = i >> 2;
    int il  = i & 3;
    int kk0 = il * 32 + gq * 8;
    *(uint4*)((__bf16*)Bp + (size_t)c * (O_DIM * KC) + o * KC + kk0) = w.v;
}

// ---------------------------------------------------------------------------
// Fused: features -> bf16 MFMA GEMM (B frags direct from L2) -> bias -> LN
// Grid: 512 blocks x 256 threads (2 blocks/CU). Block tile 32n x 128o.
// A double-buffered in LDS; one barrier per chunk; x reloaded per chunk
// (L1-resident, 4 B/thread). Wave tile: 32n x 32o (2 m x 2 o of 16x16x32).
// Feature staging: waves 0-1 compute harmonics f=1..8, waves 2-3 f=9..16
// (wave-uniform split -> no divergence).
// ---------------------------------------------------------------------------
__global__ __launch_bounds__(256) void fkan_main(
    const float* __restrict__ x,
    const __hip_bfloat16* __restrict__ Bp,
    const float* __restrict__ bias,
    const float* __restrict__ gamma,
    const float* __restrict__ beta,
    float* __restrict__ out)
{
    // LDS: 2 x (32 x 136 bf16) = 17408 B; epilogue C (32 x 132 f32 = 16896 B)
    // overlays the same region.
    __shared__ __align__(16) char smem[2 * BN * A_STRIDE * 2];
    __bf16* As = (__bf16*)smem;
    float*  Cs = (float*)smem;

    const int t     = threadIdx.x;
    const int lane  = t & 63;
    const int wave  = t >> 6;
    const int row16 = lane & 15;
    const int quad  = lane >> 4;
    const int n0    = blockIdx.x * BN;

    // feature staging: pair p = t & 127 -> (fn = p>>2, fil = p&3); half = t>>7
    const int fn   = (t & 127) >> 2;
    const int fil  = t & 3;
    const int half = t >> 7;            // wave-uniform: 0 for waves 0-1, 1 for 2-3

    f32x4 acc[2][2];
#pragma unroll
    for (int mt = 0; mt < 2; ++mt)
#pragma unroll
        for (int ot = 0; ot < 2; ++ot)
            acc[mt][ot] = (f32x4){0.f, 0.f, 0.f, 0.f};

    // ---- stage 16 harmonics (this thread's half) for chunk c ----
    auto stage_feats = [&](int c, int buf) {
        float xv = x[(size_t)(n0 + fn) * I_DIM + c * 4 + fil];
        float s1, c1;
        __sincosf(xv, &s1, &c1);
        float ck, sk;
        if (half == 0) {                 // start at f=1
            ck = c1; sk = s1;
        } else {                         // start at f=9 via doublings
            float c2 = c1 * c1 - s1 * s1, s2 = 2.f * c1 * s1;
            float c4 = c2 * c2 - s2 * s2, s4 = 2.f * c2 * s2;
            float c8 = c4 * c4 - s4 * s4, s8 = 2.f * c4 * s4;
            ck = c8 * c1 - s8 * s1;
            sk = s8 * c1 + c8 * s1;
        }
        union { __bf16 h[16]; bf16x8 v[2]; } f;
        f.h[0] = (__bf16)ck; f.h[1] = (__bf16)sk;
#pragma unroll
        for (int j = 1; j < 8; ++j) {
            float cn = ck * c1 - sk * s1;
            float sn = sk * c1 + ck * s1;
            f.h[2 * j]     = (__bf16)cn;
            f.h[2 * j + 1] = (__bf16)sn;
            ck = cn; sk = sn;
        }
        bf16x8* dst = (bf16x8*)(As + buf * (BN * A_STRIDE) + fn * A_STRIDE + fil * 32 + half * 16);
        dst[0] = f.v[0];
        dst[1] = f.v[1];
    };

    stage_feats(0, 0);
    __syncthreads();

    const __bf16* Bw = (const __bf16*)Bp + (size_t)wave * 32 * KC;  // this wave's o-slice

    for (int c = 0; c < NCHUNK; ++c) {
        const int buf = c & 1;

        // ---- B fragments for chunk c: direct global (L2/L1) -> VGPR ----
        bf16x8 bfrag[4][2];
        {
            const __bf16* Bq = Bw + (size_t)c * (O_DIM * KC);
#pragma unroll
            for (int ks = 0; ks < 4; ++ks)
#pragma unroll
                for (int ot = 0; ot < 2; ++ot)
                    bfrag[ks][ot] = *(const bf16x8*)(Bq + (ot * 16 + row16) * KC + ks * 32 + quad * 8);
        }

        // ---- stage features for chunk c+1 into the other buffer ----
        if (c + 1 < NCHUNK) stage_feats(c + 1, buf ^ 1);

        // ---- MFMA: 4 ksteps x (2 m-tiles x 2 o-tiles) ----
        const __bf16* Ab = As + buf * (BN * A_STRIDE);
#pragma unroll
        for (int ks = 0; ks < 4; ++ks) {
            bf16x8 a[2];
#pragma unroll
            for (int mt = 0; mt < 2; ++mt)
                a[mt] = *(const bf16x8*)(Ab + (mt * 16 + row16) * A_STRIDE + ks * 32 + quad * 8);
#pragma unroll
            for (int mt = 0; mt < 2; ++mt)
#pragma unroll
                for (int ot = 0; ot < 2; ++ot)
                    acc[mt][ot] = __builtin_amdgcn_mfma_f32_16x16x32_bf16(
                        a[mt], bfrag[ks][ot], acc[mt][ot], 0, 0, 0);
        }
        __syncthreads();
    }

    // ---- epilogue: C -> LDS, bias + LayerNorm over O=128, store fp32 ----
    // C/D layout: col(o within 16) = lane&15, row(m within 16) = quad*4 + reg
#pragma unroll
    for (int mt = 0; mt < 2; ++mt)
#pragma unroll
        for (int ot = 0; ot < 2; ++ot)
#pragma unroll
            for (int r = 0; r < 4; ++r)
                Cs[(mt * 16 + quad * 4 + r) * C_STRIDE + wave * 32 + ot * 16 + row16] =
                    acc[mt][ot][r];
    __syncthreads();

    {
        const int r  = t >> 3;   // row within block (0..31)
        const int qt = t & 7;    // eighth of the O dim (16 outputs each)
        const float* crow = Cs + r * C_STRIDE + qt * 16;
        float vals[16];
        float sum = 0.f, sumsq = 0.f;
#pragma unroll
        for (int j = 0; j < 16; ++j) {
            float v = crow[j] + bias[qt * 16 + j];
            vals[j] = v;
            sum += v;
            sumsq += v * v;
        }
        sum   += __shfl_xor(sum, 1);   sum   += __shfl_xor(sum, 2);   sum   += __shfl_xor(sum, 4);
        sumsq += __shfl_xor(sumsq, 1); sumsq += __shfl_xor(sumsq, 2); sumsq += __shfl_xor(sumsq, 4);
        float mu  = sum * (1.0f / O_DIM);
        float var = sumsq * (1.0f / O_DIM) - mu * mu;
        float rstd = rsqrtf(var + 1e-5f);

        float* orow = out + (size_t)(n0 + r) * O_DIM + qt * 16;
#pragma unroll
        for (int jj = 0; jj < 4; ++jj) {
            float4 o4;
            o4.x = (vals[4 * jj + 0] - mu) * rstd * gamma[qt * 16 + 4 * jj + 0] + beta[qt * 16 + 4 * jj + 0];
            o4.y = (vals[4 * jj + 1] - mu) * rstd * gamma[qt * 16 + 4 * jj + 1] + beta[qt * 16 + 4 * jj + 1];
            o4.z = (vals[4 * jj + 2] - mu) * rstd * gamma[qt * 16 + 4 * jj + 2] + beta[qt * 16 + 4 * jj + 2];
            o4.w = (vals[4 * jj + 3] - mu) * rstd * gamma[qt * 16 + 4 * jj + 3] + beta[qt * 16 + 4 * jj + 3];
            *(float4*)(orow + 4 * jj) = o4;
        }
    }
}

extern "C" void kernel_launch(void* const* d_in, const int* in_sizes, int n_in,
                              void* d_out, int out_size, void* d_ws, size_t ws_size,
                              hipStream_t stream) {
    const float* x     = (const float*)d_in[0];
    const float* cosA  = (const float*)d_in[1];
    const float* sinA  = (const float*)d_in[2];
    const float* bias  = (const float*)d_in[3];
    const float* gamma = (const float*)d_in[4];
    const float* beta  = (const float*)d_in[5];
    float* out = (float*)d_out;

    __hip_bfloat16* Bp = (__hip_bfloat16*)d_ws;   // 1 MB: 32 chunks x 128 o x 128 k

    fkan_pack_b<<<dim3((O_DIM * I_DIM * 4) / 256), dim3(256), 0, stream>>>(cosA, sinA, Bp);
    fkan_main<<<dim3(N_TOK / BN), dim3(256), 0, stream>>>(x, Bp, bias, gamma, beta, out);
}